// Round 2
// baseline (362.092 us; speedup 1.0000x reference)
//
#include <hip/hip_runtime.h>
#include <hip/hip_cooperative_groups.h>

namespace cg = cooperative_groups;

#define B_ 4
#define C_ 64
#define IC_ 32
#define N_ 4096
#define LOG2E 1.44269504088896341f

typedef __attribute__((ext_vector_type(8))) short short8;
typedef __attribute__((ext_vector_type(4))) float floatx4;

__device__ __forceinline__ unsigned short f2bf(float f) {
  unsigned u = __float_as_uint(f);
  u += 0x7FFFu + ((u >> 16) & 1u);   // round-to-nearest-even
  return (unsigned short)(u >> 16);
}
__device__ __forceinline__ float bf2f(unsigned short h) {
  return __uint_as_float(((unsigned)h) << 16);
}

struct Params {
  const float* x;
  const float* d1_w; const float* d1_b;
  const float* d2_w; const float* d2_b;
  const float* d3_w; const float* d3_b;
  const float* g_w;  const float* g_b;
  const float* th_w; const float* th_b;
  const float* ph_w; const float* ph_b;
  const float* w_w;  const float* w_b;
  float* out;
  unsigned short* am_cl; unsigned short* thph; unsigned short* g16;
  float* lpart; unsigned short* y2p;
  unsigned short* wpk; unsigned short* wproj; float* bproj;
  unsigned short* xclp; unsigned short* y1clp; unsigned short* y2clp;
};

#define SMEM_BYTES 42496

// ---------------- phase 0: pack x -> padded cl bf16; weights -> bf16; zero pads ------
__device__ __forceinline__ void phase_pack(const Params& p, char* smem) {
  const int bid = blockIdx.x, t = threadIdx.x;
  // x transpose: each block handles one (b,h)
  {
    float (*s)[65] = reinterpret_cast<float(*)[65]>(smem);
    const int b = bid >> 6, h = bid & 63;
    for (int idx = t; idx < 4096; idx += 256) {
      int c = idx >> 6, w = idx & 63;
      s[c][w] = p.x[((size_t)(b * 64 + c)) * 4096 + h * 64 + w];
    }
    __syncthreads();
    for (int idx = t; idx < 4096; idx += 256) {
      int w = idx >> 6, c = idx & 63;
      p.xclp[(((size_t)b * 66 + h + 1) * 66 + (w + 1)) * 64 + c] = f2bf(s[c][w]);
    }
  }
  const int gt = bid * 256 + t;   // 0..65535
  // conv weights
  for (int idx = gt; idx < 3 * 36864; idx += 65536) {
    int cv = idx / 36864, r = idx % 36864;
    int tap = r / 4096, r2 = r % 4096;
    int oc = r2 >> 6, ic = r2 & 63;
    const float* src = (cv == 0) ? p.d1_w : (cv == 1) ? p.d2_w : p.d3_w;
    p.wpk[(size_t)cv * 36864 + tap * 4096 + oc * 64 + ic] = f2bf(src[oc * 576 + ic * 9 + tap]);
  }
  // 1x1 proj weights
  if (gt < 6144) {
    int m = gt >> 6, ic = gt & 63;
    float v = (m < 32) ? LOG2E * p.th_w[m * 64 + ic]
            : (m < 64) ? p.ph_w[(m - 32) * 64 + ic]
                       : p.g_w[(m - 64) * 64 + ic];
    p.wproj[m * 64 + ic] = f2bf(v);
  }
  if (gt < 96)
    p.bproj[gt] = (gt < 32) ? LOG2E * p.th_b[gt] : (gt < 64) ? p.ph_b[gt - 32] : p.g_b[gt - 64];
  // zero xclp border pixels (128 B each)
  uint4 z4 = {0u, 0u, 0u, 0u};
  if (gt < 4 * 66 * 66) {
    int r = gt % 4356, h = r / 66, w = r % 66;
    if (h == 0 || h == 65 || w == 0 || w == 65) {
      uint4* d = reinterpret_cast<uint4*>(p.xclp + (size_t)gt * 64);
#pragma unroll
      for (int q = 0; q < 8; ++q) d[q] = z4;
    }
  }
  // zero y1clp / y2clp fully (interiors rewritten by conv phases)
  if (gt < 36992) reinterpret_cast<uint4*>(p.y1clp)[gt] = z4;
  if (gt < 10368) reinterpret_cast<uint4*>(p.y2clp)[gt] = z4;
}

// ---------------- implicit-GEMM conv 3x3 s2, 64->64 ch (one wave-task) ---------------
template<int IN_PW, int OUT_H>
__device__ __forceinline__ void phase_conv(const unsigned short* xin, const unsigned short* wp,
                                           const float* bias, unsigned short* obf, int wid, int lane) {
  constexpr int NTILES = OUT_H * OUT_H / 16;
  const int n15 = lane & 15, quad = lane >> 4;
  int bx = wid;
  const int octile = bx & 3; bx >>= 2;
  const int otile = bx % NTILES;
  const int b = bx / NTILES;
  const int o = otile * 16 + n15;
  const int oh = o / OUT_H, ow = o % OUT_H;
  const unsigned short* xb = xin + (size_t)b * IN_PW * IN_PW * 64;
  floatx4 acc = {0.f, 0.f, 0.f, 0.f};
#pragma unroll
  for (int tap = 0; tap < 9; ++tap) {
    const int kh = tap / 3, kw = tap % 3;
    const unsigned short* xpix = xb + ((size_t)(oh * 2 + kh) * IN_PW + (ow * 2 + kw)) * 64;
#pragma unroll
    for (int ks = 0; ks < 2; ++ks) {
      short8 af = *reinterpret_cast<const short8*>(
          wp + ((size_t)tap * 64 + octile * 16 + n15) * 64 + ks * 32 + quad * 8);
      short8 bf = *reinterpret_cast<const short8*>(xpix + ks * 32 + quad * 8);
      acc = __builtin_amdgcn_mfma_f32_16x16x32_bf16(af, bf, acc, 0, 0, 0);
    }
  }
  const float4 bv = *reinterpret_cast<const float4*>(bias + octile * 16 + quad * 4);
  float v[4] = {acc[0] + bv.x, acc[1] + bv.y, acc[2] + bv.z, acc[3] + bv.w};
#pragma unroll
  for (int r = 0; r < 4; ++r) v[r] = (v[r] >= 0.f) ? v[r] : 0.2f * v[r];   // lrelu
  constexpr int OPW = OUT_H + 2;
  unsigned short pk[4];
#pragma unroll
  for (int r = 0; r < 4; ++r) pk[r] = f2bf(v[r]);
  *reinterpret_cast<uint2*>(
      obf + (((size_t)b * OPW + oh + 1) * OPW + (ow + 1)) * 64 + octile * 16 + quad * 4) =
      *reinterpret_cast<uint2*>(pk);
}

// ------- phase 3: conv3(8x8) on the fly + bilinear upsample + sigmoid gate + 1x1 proj ----
__device__ __forceinline__ void phase_upsproj(const Params& p, char* smem) {
  const int bid = blockIdx.x, t = threadIdx.x;
  const int b = bid >> 6, oh = bid & 63;
  float* s0 = reinterpret_cast<float*>(smem);          // 512 f
  float* s1 = s0 + 512;                                // 512 f
  unsigned short* s_am = reinterpret_cast<unsigned short*>(smem + 4096);   // [64][72]
  const unsigned short* wp3 = p.wpk + 2 * 36864;
  float sh = (oh + 0.5f) * 0.125f - 0.5f;
  float fh = floorf(sh); float ah = sh - fh; int h0 = (int)fh;
  int h0c = min(7, max(0, h0)), h1c = min(7, max(0, h0 + 1));
  // conv3 (no lrelu) rows h0c,h1c -> s0,s1
  {
    const int wave = t >> 6, lane = t & 63;
    const int n15 = lane & 15, quad = lane >> 4;
    const int hrow = (n15 < 8) ? h0c : h1c;
    const int ow8 = n15 & 7;
    const unsigned short* xb2 = p.y2clp + (size_t)b * 18 * 18 * 64;
    floatx4 acc = {0.f, 0.f, 0.f, 0.f};
#pragma unroll
    for (int tap = 0; tap < 9; ++tap) {
      const int kh = tap / 3, kw = tap % 3;
      const unsigned short* xpix = xb2 + ((size_t)(hrow * 2 + kh) * 18 + (ow8 * 2 + kw)) * 64;
#pragma unroll
      for (int ks = 0; ks < 2; ++ks) {
        short8 af = *reinterpret_cast<const short8*>(
            wp3 + ((size_t)tap * 64 + wave * 16 + n15) * 64 + ks * 32 + quad * 8);
        short8 bf = *reinterpret_cast<const short8*>(xpix + ks * 32 + quad * 8);
        acc = __builtin_amdgcn_mfma_f32_16x16x32_bf16(af, bf, acc, 0, 0, 0);
      }
    }
    const float4 bv = *reinterpret_cast<const float4*>(p.d3_b + wave * 16 + quad * 4);
    float4 st = {acc[0] + bv.x, acc[1] + bv.y, acc[2] + bv.z, acc[3] + bv.w};
    float* dst = (n15 < 8) ? s0 : s1;
    *reinterpret_cast<float4*>(&dst[(size_t)ow8 * 64 + wave * 16 + quad * 4]) = st;
  }
  __syncthreads();
  {
    const int ow = t >> 2, cq = t & 3;
    float sw = (ow + 0.5f) * 0.125f - 0.5f;
    float fw = floorf(sw); float aw = sw - fw; int w0 = (int)fw;
    int w0c = min(7, max(0, w0)), w1c = min(7, max(0, w0 + 1));
    const int n = oh * 64 + ow;
    const float* xb = p.x + (size_t)b * 64 * 4096 + n;
    unsigned short* ap = p.am_cl + ((size_t)b * N_ + n) * 64 + cq * 16;
#pragma unroll
    for (int u = 0; u < 4; ++u) {
      int c0 = cq * 16 + u * 4;
      float4 a00 = *reinterpret_cast<const float4*>(&s0[w0c * 64 + c0]);
      float4 a01 = *reinterpret_cast<const float4*>(&s0[w1c * 64 + c0]);
      float4 a10 = *reinterpret_cast<const float4*>(&s1[w0c * 64 + c0]);
      float4 a11 = *reinterpret_cast<const float4*>(&s1[w1c * 64 + c0]);
      float i0[4] = {a00.x * (1.f - aw) + a01.x * aw, a00.y * (1.f - aw) + a01.y * aw,
                     a00.z * (1.f - aw) + a01.z * aw, a00.w * (1.f - aw) + a01.w * aw};
      float i1[4] = {a10.x * (1.f - aw) + a11.x * aw, a10.y * (1.f - aw) + a11.y * aw,
                     a10.z * (1.f - aw) + a11.z * aw, a10.w * (1.f - aw) + a11.w * aw};
      unsigned short pk[4];
#pragma unroll
      for (int vi = 0; vi < 4; ++vi) {
        float vv = i0[vi] * (1.f - ah) + i1[vi] * ah;
        float xv = xb[(size_t)(c0 + vi) * 4096];
        float sig = 1.f / (1.f + __expf(-vv));
        pk[vi] = f2bf(sig * xv);
      }
      uint2 pkt = *reinterpret_cast<uint2*>(pk);
      *reinterpret_cast<uint2*>(ap + u * 4) = pkt;
      *reinterpret_cast<uint2*>(&s_am[ow * 72 + c0]) = pkt;
    }
  }
  __syncthreads();
  const int wave = t >> 6, lane = t & 63;
  const int n15 = lane & 15, quad = lane >> 4;
  const int n = oh * 64 + wave * 16 + n15;
  const unsigned short* srow = &s_am[(wave * 16 + n15) * 72];
  const short8 bf0 = *reinterpret_cast<const short8*>(srow + quad * 8);
  const short8 bf1 = *reinterpret_cast<const short8*>(srow + 32 + quad * 8);
#pragma unroll
  for (int mt = 0; mt < 6; ++mt) {
    short8 a0 = *reinterpret_cast<const short8*>(p.wproj + ((size_t)mt * 16 + n15) * 64 + quad * 8);
    short8 a1 = *reinterpret_cast<const short8*>(p.wproj + ((size_t)mt * 16 + n15) * 64 + 32 + quad * 8);
    floatx4 acc = {0.f, 0.f, 0.f, 0.f};
    acc = __builtin_amdgcn_mfma_f32_16x16x32_bf16(a0, bf0, acc, 0, 0, 0);
    acc = __builtin_amdgcn_mfma_f32_16x16x32_bf16(a1, bf1, acc, 0, 0, 0);
    const float4 bv = *reinterpret_cast<const float4*>(p.bproj + mt * 16 + quad * 4);
    float v[4] = {acc[0] + bv.x, acc[1] + bv.y, acc[2] + bv.z, acc[3] + bv.w};
    if (mt < 4) {
      unsigned short pk[4];
#pragma unroll
      for (int r = 0; r < 4; ++r) pk[r] = f2bf(v[r]);
      *reinterpret_cast<uint2*>(p.thph + ((size_t)b * N_ + n) * 64 + mt * 16 + quad * 4) =
          *reinterpret_cast<uint2*>(pk);
    } else {
#pragma unroll
      for (int r = 0; r < 4; ++r)
        p.g16[((size_t)b * 32 + (mt - 4) * 16 + quad * 4 + r) * N_ + n] = f2bf(v[r]);
    }
  }
}

// ---------------- phase 4: l_j partials, batched 4 j-tasks per wave ------------------
__device__ __forceinline__ void phase_stats(const Params& p, int wid, int lane) {
  const int n15 = lane & 15, quad = lane >> 4;
  const int iz = wid >> 6, b = (wid >> 4) & 3, jc = wid & 15;
  const int j0 = jc * 256;
  const unsigned short* base = p.thph + (size_t)b * N_ * 64;
  short8 bv[16];
#pragma unroll
  for (int v = 0; v < 16; ++v)
    bv[v] = *reinterpret_cast<const short8*>(base + (size_t)(j0 + v * 16 + n15) * 64 + 32 + quad * 8);
  float ls[16];
#pragma unroll
  for (int v = 0; v < 16; ++v) ls[v] = 0.f;
  const unsigned short* ap = base + (size_t)(iz * 256 + n15) * 64 + quad * 8;
  short8 ac = *reinterpret_cast<const short8*>(ap);
  for (int st = 0; st < 16; ++st) {
    short8 an = *reinterpret_cast<const short8*>(ap + (size_t)((st < 15) ? st + 1 : st) * 1024);
#pragma unroll
    for (int v = 0; v < 16; ++v) {
      floatx4 z = {0.f, 0.f, 0.f, 0.f};
      z = __builtin_amdgcn_mfma_f32_16x16x32_bf16(ac, bv[v], z, 0, 0, 0);
      ls[v] += (__builtin_amdgcn_exp2f(z[0]) + __builtin_amdgcn_exp2f(z[1]))
             + (__builtin_amdgcn_exp2f(z[2]) + __builtin_amdgcn_exp2f(z[3]));
    }
    ac = an;
  }
#pragma unroll
  for (int v = 0; v < 16; ++v) {
    ls[v] += __shfl_xor(ls[v], 16);
    ls[v] += __shfl_xor(ls[v], 32);
  }
  if (quad == 0) {
#pragma unroll
    for (int v = 0; v < 16; ++v)
      p.lpart[((size_t)iz * B_ + b) * N_ + j0 + v * 16 + n15] = ls[v];
  }
}

// ---------------- phase 5: PV with in-kernel softmax-denominator fold ----------------
#define PHI_PITCH 40
#define G_PITCH   136
__device__ __forceinline__ void phase_pv(const Params& p, char* smem) {
  const int bid = blockIdx.x, t = threadIdx.x;
  const int wave = t >> 6, lane = t & 63;
  const int n15 = lane & 15, quad = lane >> 4;
  const int ixp = bid & 15, b = (bid >> 4) & 3, jq = bid >> 6;
  unsigned short* phi_lds = reinterpret_cast<unsigned short*>(smem);            // [2][128*40]
  unsigned short* g_lds   = reinterpret_cast<unsigned short*>(smem + 20480);    // [2][32*136]
  float* rl_lds           = reinterpret_cast<float*>(smem + 37888);             // [1024]
  const unsigned short* base = p.thph + (size_t)b * N_ * 64;
  const unsigned short* gs   = p.g16  + (size_t)b * 32 * N_;
  const int jbase = jq * 1024;
  // softmax denominators for this 1024-j window
  for (int jj = t; jj < 1024; jj += 256) {
    float l = 0.f;
#pragma unroll
    for (int iz = 0; iz < 16; ++iz) l += p.lpart[((size_t)iz * B_ + b) * N_ + jbase + jj];
    rl_lds[jj] = 1.f / l;
  }
  const int iw = ixp * 256 + wave * 32;
  const short8 bthA0 = *reinterpret_cast<const short8*>(base + (size_t)(iw + n15) * 64 + quad * 8);
  const short8 bthA1 = *reinterpret_cast<const short8*>(base + (size_t)(iw + 16 + n15) * 64 + quad * 8);
  const short8 bthB0 = *reinterpret_cast<const short8*>(base + (size_t)(iw + 128 + n15) * 64 + quad * 8);
  const short8 bthB1 = *reinterpret_cast<const short8*>(base + (size_t)(iw + 144 + n15) * 64 + quad * 8);
  floatx4 YA00 = {0,0,0,0}, YA01 = {0,0,0,0}, YA10 = {0,0,0,0}, YA11 = {0,0,0,0};
  floatx4 YB00 = {0,0,0,0}, YB01 = {0,0,0,0}, YB10 = {0,0,0,0}, YB11 = {0,0,0,0};
  const int rphi = wave * 32 + (lane >> 2), cph = lane & 3;
  const int cg_  = wave * 8  + (lane >> 4), chg = lane & 15;
  uint4 sp0, sp1, sg0, sg1;
  sp0 = *reinterpret_cast<const uint4*>(base + (size_t)(jbase + rphi) * 64 + 32 + cph * 8);
  sp1 = *reinterpret_cast<const uint4*>(base + (size_t)(jbase + rphi + 16) * 64 + 32 + cph * 8);
  sg0 = *reinterpret_cast<const uint4*>(gs + (size_t)cg_ * N_ + jbase + chg * 8);
  sg1 = *reinterpret_cast<const uint4*>(gs + (size_t)(cg_ + 4) * N_ + jbase + chg * 8);
  *reinterpret_cast<uint4*>(&phi_lds[rphi * PHI_PITCH + cph * 8]) = sp0;
  *reinterpret_cast<uint4*>(&phi_lds[(rphi + 16) * PHI_PITCH + cph * 8]) = sp1;
  *reinterpret_cast<uint4*>(&g_lds[cg_ * G_PITCH + chg * 8]) = sg0;
  *reinterpret_cast<uint4*>(&g_lds[(cg_ + 4) * G_PITCH + chg * 8]) = sg1;
  __syncthreads();
  int j0 = jbase;
  for (int ch = 0; ch < 8; ++ch, j0 += 128) {
    const int cur = ch & 1;
    if (ch < 7) {
      const int jn = j0 + 128;
      sp0 = *reinterpret_cast<const uint4*>(base + (size_t)(jn + rphi) * 64 + 32 + cph * 8);
      sp1 = *reinterpret_cast<const uint4*>(base + (size_t)(jn + rphi + 16) * 64 + 32 + cph * 8);
      sg0 = *reinterpret_cast<const uint4*>(gs + (size_t)cg_ * N_ + jn + chg * 8);
      sg1 = *reinterpret_cast<const uint4*>(gs + (size_t)(cg_ + 4) * N_ + jn + chg * 8);
    }
    const unsigned short* phb = phi_lds + cur * (128 * PHI_PITCH);
    const unsigned short* glb = g_lds + cur * (32 * G_PITCH);
#pragma unroll
    for (int sg_ = 0; sg_ < 4; ++sg_) {
      unsigned pkA0[4], pkA1[4], pkB0[4], pkB1[4];
#pragma unroll
      for (int jtl = 0; jtl < 2; ++jtl) {
        const int jt = sg_ * 2 + jtl;
        short8 aph = *reinterpret_cast<const short8*>(phb + (jt * 16 + n15) * PHI_PITCH + quad * 8);
        float4 rlv = *reinterpret_cast<const float4*>(&rl_lds[ch * 128 + jt * 16 + quad * 4]);
        floatx4 zA0 = {0,0,0,0}, zA1 = {0,0,0,0}, zB0 = {0,0,0,0}, zB1 = {0,0,0,0};
        zA0 = __builtin_amdgcn_mfma_f32_16x16x32_bf16(aph, bthA0, zA0, 0, 0, 0);
        zA1 = __builtin_amdgcn_mfma_f32_16x16x32_bf16(aph, bthA1, zA1, 0, 0, 0);
        zB0 = __builtin_amdgcn_mfma_f32_16x16x32_bf16(aph, bthB0, zB0, 0, 0, 0);
        zB1 = __builtin_amdgcn_mfma_f32_16x16x32_bf16(aph, bthB1, zB1, 0, 0, 0);
#define PK_(Z, PK)                                                                  \
        {                                                                           \
          float e0 = __builtin_amdgcn_exp2f(Z[0]) * rlv.x;                          \
          float e1 = __builtin_amdgcn_exp2f(Z[1]) * rlv.y;                          \
          float e2 = __builtin_amdgcn_exp2f(Z[2]) * rlv.z;                          \
          float e3 = __builtin_amdgcn_exp2f(Z[3]) * rlv.w;                          \
          PK[jtl * 2 + 0] = __builtin_amdgcn_perm(__float_as_uint(e1), __float_as_uint(e0), 0x07060302); \
          PK[jtl * 2 + 1] = __builtin_amdgcn_perm(__float_as_uint(e3), __float_as_uint(e2), 0x07060302); \
        }
        PK_(zA0, pkA0) PK_(zA1, pkA1) PK_(zB0, pkB0) PK_(zB1, pkB1)
#undef PK_
      }
      union U8 { unsigned u[4]; short8 v; };
      U8 paA0, paA1, paB0, paB1, gb0, gb1;
#pragma unroll
      for (int q = 0; q < 4; ++q) {
        paA0.u[q] = pkA0[q]; paA1.u[q] = pkA1[q];
        paB0.u[q] = pkB0[q]; paB1.u[q] = pkB1[q];
      }
      const unsigned short* gr0 = glb + n15 * G_PITCH + sg_ * 32 + quad * 4;
      const unsigned short* gr1 = glb + (16 + n15) * G_PITCH + sg_ * 32 + quad * 4;
      uint2 lo0 = *reinterpret_cast<const uint2*>(gr0);
      uint2 hi0 = *reinterpret_cast<const uint2*>(gr0 + 16);
      uint2 lo1 = *reinterpret_cast<const uint2*>(gr1);
      uint2 hi1 = *reinterpret_cast<const uint2*>(gr1 + 16);
      gb0.u[0] = lo0.x; gb0.u[1] = lo0.y; gb0.u[2] = hi0.x; gb0.u[3] = hi0.y;
      gb1.u[0] = lo1.x; gb1.u[1] = lo1.y; gb1.u[2] = hi1.x; gb1.u[3] = hi1.y;
      YA00 = __builtin_amdgcn_mfma_f32_16x16x32_bf16(paA0.v, gb0.v, YA00, 0, 0, 0);
      YA01 = __builtin_amdgcn_mfma_f32_16x16x32_bf16(paA0.v, gb1.v, YA01, 0, 0, 0);
      YA10 = __builtin_amdgcn_mfma_f32_16x16x32_bf16(paA1.v, gb0.v, YA10, 0, 0, 0);
      YA11 = __builtin_amdgcn_mfma_f32_16x16x32_bf16(paA1.v, gb1.v, YA11, 0, 0, 0);
      YB00 = __builtin_amdgcn_mfma_f32_16x16x32_bf16(paB0.v, gb0.v, YB00, 0, 0, 0);
      YB01 = __builtin_amdgcn_mfma_f32_16x16x32_bf16(paB0.v, gb1.v, YB01, 0, 0, 0);
      YB10 = __builtin_amdgcn_mfma_f32_16x16x32_bf16(paB1.v, gb0.v, YB10, 0, 0, 0);
      YB11 = __builtin_amdgcn_mfma_f32_16x16x32_bf16(paB1.v, gb1.v, YB11, 0, 0, 0);
    }
    if (ch < 7) {
      const int nb = cur ^ 1;
      *reinterpret_cast<uint4*>(&phi_lds[nb * (128 * PHI_PITCH) + rphi * PHI_PITCH + cph * 8]) = sp0;
      *reinterpret_cast<uint4*>(&phi_lds[nb * (128 * PHI_PITCH) + (rphi + 16) * PHI_PITCH + cph * 8]) = sp1;
      *reinterpret_cast<uint4*>(&g_lds[nb * (32 * G_PITCH) + cg_ * G_PITCH + chg * 8]) = sg0;
      *reinterpret_cast<uint4*>(&g_lds[nb * (32 * G_PITCH) + (cg_ + 4) * G_PITCH + chg * 8]) = sg1;
    }
    __syncthreads();
  }
  const size_t orow = ((size_t)jq * B_ + b) * 32;
#define STY_(Y, ROW, COL)                                                            \
  {                                                                                  \
    unsigned w_[2];                                                                  \
    w_[0] = ((unsigned)f2bf(Y[1]) << 16) | f2bf(Y[0]);                               \
    w_[1] = ((unsigned)f2bf(Y[3]) << 16) | f2bf(Y[2]);                               \
    *reinterpret_cast<uint2*>(p.y2p + (size_t)(ROW) * N_ + (COL) + quad * 4) =       \
        *reinterpret_cast<uint2*>(w_);                                               \
  }
  STY_(YA00, orow + n15,      iw)
  STY_(YA01, orow + 16 + n15, iw)
  STY_(YA10, orow + n15,      iw + 16)
  STY_(YA11, orow + 16 + n15, iw + 16)
  STY_(YB00, orow + n15,      iw + 128)
  STY_(YB01, orow + 16 + n15, iw + 128)
  STY_(YB10, orow + n15,      iw + 144)
  STY_(YB11, orow + 16 + n15, iw + 144)
#undef STY_
}

// ---------------- phase 6: out = (W_y(y2) + am) * x ----------------
__device__ __forceinline__ void phase_final(const Params& p) {
  const int bid = blockIdx.x;
  const int xb_ = bid & 7, ob = (bid >> 3) & 7, b = bid >> 6;
  const int n0 = (xb_ * 256 + (int)threadIdx.x) * 2;
  const int o0 = ob * 8;
  float a0[8], a1[8];
#pragma unroll
  for (int u = 0; u < 8; ++u) { a0[u] = p.w_b[o0 + u]; a1[u] = a0[u]; }
  for (int c = 0; c < 32; ++c) {
    float s0 = 0.f, s1 = 0.f;
#pragma unroll
    for (int ph = 0; ph < 4; ++ph) {
      unsigned v = *reinterpret_cast<const unsigned*>(
          p.y2p + (((size_t)ph * B_ + b) * 32 + c) * N_ + n0);
      s0 += bf2f((unsigned short)(v & 0xffffu));
      s1 += bf2f((unsigned short)(v >> 16));
    }
#pragma unroll
    for (int u = 0; u < 8; ++u) {
      float wv = p.w_w[(o0 + u) * 32 + c];
      a0[u] += wv * s0; a1[u] += wv * s1;
    }
  }
  const short8 am0 = *reinterpret_cast<const short8*>(p.am_cl + ((size_t)b * N_ + n0) * 64 + o0);
  const short8 am1 = *reinterpret_cast<const short8*>(p.am_cl + ((size_t)b * N_ + n0 + 1) * 64 + o0);
#pragma unroll
  for (int u = 0; u < 8; ++u) {
    size_t off = ((size_t)b * 64 + o0 + u) * N_ + n0;
    float2 xv = *reinterpret_cast<const float2*>(p.x + off);
    float2 ov;
    ov.x = (a0[u] + bf2f((unsigned short)am0[u])) * xv.x;
    ov.y = (a1[u] + bf2f((unsigned short)am1[u])) * xv.y;
    *reinterpret_cast<float2*>(p.out + off) = ov;
  }
}

// ---------------- the cooperative mega-kernel ----------------
__global__ void __launch_bounds__(256, 1) mega_k(Params p) {
  __shared__ __align__(16) char smem[SMEM_BYTES];
  cg::grid_group grid = cg::this_grid();
  const int bid = blockIdx.x, t = threadIdx.x;
  const int wave = t >> 6, lane = t & 63;
  phase_pack(p, smem);
  grid.sync();
  phase_conv<66, 32>(p.xclp, p.wpk, p.d1_b, p.y1clp, bid * 4 + wave, lane);
  grid.sync();
  { int wid = bid * 4 + wave;
    if (wid < 256) phase_conv<34, 16>(p.y1clp, p.wpk + 36864, p.d2_b, p.y2clp, wid, lane); }
  grid.sync();
  phase_upsproj(p, smem);
  grid.sync();
  phase_stats(p, bid * 4 + wave, lane);
  grid.sync();
  phase_pv(p, smem);
  grid.sync();
  phase_final(p);
}

// ---------------- non-cooperative fallback wrappers ----------------
__global__ void __launch_bounds__(256) ph0_k(Params p) {
  __shared__ __align__(16) char smem[SMEM_BYTES];
  phase_pack(p, smem);
}
__global__ void __launch_bounds__(256) ph1_k(Params p) {
  phase_conv<66, 32>(p.xclp, p.wpk, p.d1_b, p.y1clp,
                     blockIdx.x * 4 + (threadIdx.x >> 6), threadIdx.x & 63);
}
__global__ void __launch_bounds__(256) ph2_k(Params p) {
  int wid = blockIdx.x * 4 + (threadIdx.x >> 6);
  if (wid < 256) phase_conv<34, 16>(p.y1clp, p.wpk + 36864, p.d2_b, p.y2clp, wid, threadIdx.x & 63);
}
__global__ void __launch_bounds__(256) ph3_k(Params p) {
  __shared__ __align__(16) char smem[SMEM_BYTES];
  phase_upsproj(p, smem);
}
__global__ void __launch_bounds__(256) ph4_k(Params p) {
  phase_stats(p, blockIdx.x * 4 + (threadIdx.x >> 6), threadIdx.x & 63);
}
__global__ void __launch_bounds__(256) ph5_k(Params p) {
  __shared__ __align__(16) char smem[SMEM_BYTES];
  phase_pv(p, smem);
}
__global__ void __launch_bounds__(256) ph6_k(Params p) {
  phase_final(p);
}

extern "C" void kernel_launch(void* const* d_in, const int* in_sizes, int n_in,
                              void* d_out, int out_size, void* d_ws, size_t ws_size,
                              hipStream_t stream) {
  Params prm;
  prm.x    = (const float*)d_in[0];
  prm.d1_w = (const float*)d_in[1];  prm.d1_b = (const float*)d_in[2];
  prm.d2_w = (const float*)d_in[3];  prm.d2_b = (const float*)d_in[4];
  prm.d3_w = (const float*)d_in[5];  prm.d3_b = (const float*)d_in[6];
  prm.g_w  = (const float*)d_in[7];  prm.g_b  = (const float*)d_in[8];
  prm.th_w = (const float*)d_in[9];  prm.th_b = (const float*)d_in[10];
  prm.ph_w = (const float*)d_in[11]; prm.ph_b = (const float*)d_in[12];
  prm.w_w  = (const float*)d_in[13]; prm.w_b  = (const float*)d_in[14];
  prm.out  = (float*)d_out;

  char* p = (char*)d_ws;
  prm.am_cl = (unsigned short*)p;  p += (size_t)B_ * N_ * 64 * 2;        // 2 MB
  prm.thph  = (unsigned short*)p;  p += (size_t)B_ * N_ * 64 * 2;        // 2 MB
  prm.g16   = (unsigned short*)p;  p += (size_t)B_ * 32 * N_ * 2;        // 1 MB
  prm.lpart = (float*)p;           p += (size_t)16 * B_ * N_ * 4;        // 1 MB
  prm.y2p   = (unsigned short*)p;  p += (size_t)4 * B_ * 32 * N_ * 2;    // 4 MB
  prm.wpk   = (unsigned short*)p;  p += (size_t)3 * 36864 * 2;
  prm.wproj = (unsigned short*)p;  p += (size_t)96 * 64 * 2;
  prm.bproj = (float*)p;           p += (size_t)96 * 4;
  prm.xclp  = (unsigned short*)p;  p += (size_t)B_ * 66 * 66 * 64 * 2;
  prm.y1clp = (unsigned short*)p;  p += (size_t)B_ * 34 * 34 * 64 * 2;
  prm.y2clp = (unsigned short*)p;  p += (size_t)B_ * 18 * 18 * 64 * 2;

  void* args[] = { (void*)&prm };
  hipError_t err = hipLaunchCooperativeKernel((const void*)mega_k, dim3(256), dim3(256),
                                              args, 0, stream);
  if (err != hipSuccess) {
    (void)hipGetLastError();
    hipLaunchKernelGGL(ph0_k, dim3(256), dim3(256), 0, stream, prm);
    hipLaunchKernelGGL(ph1_k, dim3(256), dim3(256), 0, stream, prm);
    hipLaunchKernelGGL(ph2_k, dim3(256), dim3(256), 0, stream, prm);
    hipLaunchKernelGGL(ph3_k, dim3(256), dim3(256), 0, stream, prm);
    hipLaunchKernelGGL(ph4_k, dim3(256), dim3(256), 0, stream, prm);
    hipLaunchKernelGGL(ph5_k, dim3(256), dim3(256), 0, stream, prm);
    hipLaunchKernelGGL(ph6_k, dim3(256), dim3(256), 0, stream, prm);
  }
}